// Round 1
// baseline (352.874 us; speedup 1.0000x reference)
//
#include <hip/hip_runtime.h>
#include <cstdint>
#include <cstddef>

#define LOG_ALPHA -2.302585092994046f  // ln(0.1)
#define ALPHA 0.1f

__global__ void zero_kernel(float* p, int n) {
  int i = blockIdx.x * blockDim.x + threadIdx.x;
  if (i < n) p[i] = 0.f;
}

// Per column j: F0v[j] = sum_b v_b*relu(t), Dv[j] = sum_{t>0} v_b, same for w.
// t = u*x[b,j] + a + shift_j  (shift = current d estimate at step j; pass1 uses 0)
template <bool HAS_SHIFT>
__global__ __launch_bounds__(256) void col_stats_kernel(
    const float* __restrict__ x, const float* __restrict__ w,
    const float* __restrict__ v, const float* __restrict__ up,
    const float* __restrict__ ap, const float* __restrict__ shift,
    float* __restrict__ F0v, float* __restrict__ Dv,
    float* __restrict__ F0w, float* __restrict__ Dw,
    int DIM, int ROWS_PER_BLOCK) {
  const int j = blockIdx.x * blockDim.x + threadIdx.x;  // column
  const int r0 = blockIdx.y * ROWS_PER_BLOCK;
  const float u = up[0], a = ap[0];
  const float base_add = a + (HAS_SHIFT ? shift[j] : 0.f);
  float fv = 0.f, dv = 0.f, fw = 0.f, dw = 0.f;
#pragma unroll 4
  for (int r = r0; r < r0 + ROWS_PER_BLOCK; ++r) {
    float xv = x[(size_t)r * DIM + j];     // coalesced across tx
    float vb = v[r], wb = w[r];            // uniform -> s_load broadcast
    float t = fmaf(u, xv, base_add);
    float rt = fmaxf(t, 0.f);
    float m = t > 0.f ? 1.f : 0.f;
    fv = fmaf(vb, rt, fv);
    dv = fmaf(vb, m, dv);
    fw = fmaf(wb, rt, fw);
    dw = fmaf(wb, m, dw);
  }
  atomicAdd(&F0v[j], fv);
  atomicAdd(&Dv[j], dv);
  atomicAdd(&F0w[j], fw);
  atomicAdd(&Dw[j], dw);
}

// Solve d_i = F0v[i-1] + Dv[i-1]*d_{i-1}, d_0 = 0, with a 64-lane affine scan.
__global__ void scan_d_kernel(const float* __restrict__ F0v,
                              const float* __restrict__ Dv,
                              float* __restrict__ d1, int DIM) {
  const int L = threadIdx.x;  // one wave: 64 lanes
  const int S = DIM / 64;
  float A = 1.f, B = 0.f;     // map d_{segstart} -> d_{segend}: p -> B + A*p
  for (int k = 0; k < S; ++k) {
    int i = L * S + k + 1;
    if (i < DIM) {
      float a = Dv[i - 1], b = F0v[i - 1];
      B = fmaf(a, B, b);
      A = a * A;
    }
  }
  for (int off = 1; off < 64; off <<= 1) {  // inclusive composition scan
    float Ao = __shfl_up(A, off, 64);
    float Bo = __shfl_up(B, off, 64);
    if (L >= off) { B = fmaf(A, Bo, B); A = A * Ao; }
  }
  float dstart = __shfl_up(B, 1, 64);  // d at segment start = prev inclusive applied to 0
  if (L == 0) dstart = 0.f;
  float d = dstart;
  for (int k = 0; k < S; ++k) {
    int i = L * S + k + 1;
    if (i < DIM) {
      d = fmaf(Dv[i - 1], d, F0v[i - 1]);
      d1[i] = d;
    }
  }
  if (threadIdx.x == 0) d1[0] = 0.f;
}

// Second-order refine: delta_i = (F0v2[i-1]-d1[i]) + Dv2[i-1]*delta_{i-1}; then
// e_i = F0w2[i-1] + Dw2[i-1]*delta_{i-1}  (e_i = dot(w, s_i)); e_0 = 0.
__global__ void scan_e_kernel(const float* __restrict__ F0v2,
                              const float* __restrict__ Dv2,
                              const float* __restrict__ F0w2,
                              const float* __restrict__ Dw2,
                              const float* __restrict__ d1,
                              float* __restrict__ e, int DIM) {
  const int L = threadIdx.x;
  const int S = DIM / 64;
  float A = 1.f, B = 0.f;
  for (int k = 0; k < S; ++k) {
    int i = L * S + k + 1;
    if (i < DIM) {
      float a = Dv2[i - 1], b = F0v2[i - 1] - d1[i];
      B = fmaf(a, B, b);
      A = a * A;
    }
  }
  for (int off = 1; off < 64; off <<= 1) {
    float Ao = __shfl_up(A, off, 64);
    float Bo = __shfl_up(B, off, 64);
    if (L >= off) { B = fmaf(A, Bo, B); A = A * Ao; }
  }
  float dstart = __shfl_up(B, 1, 64);
  if (L == 0) dstart = 0.f;
  float delta = dstart;
  for (int k = 0; k < S; ++k) {
    int i = L * S + k + 1;
    if (i < DIM) {
      e[i] = fmaf(Dw2[i - 1], delta, F0w2[i - 1]);          // uses delta_{i-1}
      delta = fmaf(Dv2[i - 1], delta, F0v2[i - 1] - d1[i]); // advance to delta_i
    }
  }
  if (threadIdx.x == 0) e[0] = 0.f;
}

// z[b,i] = leakyrelu(y*x[b,i] + e_i + b0); log_det[b] = DIM*log|y| + cnt_neg*ln(alpha)
__global__ __launch_bounds__(256) void z_kernel(
    const float* __restrict__ x, const float* __restrict__ e,
    const float* __restrict__ yp, const float* __restrict__ bp,
    float* __restrict__ z, float* __restrict__ ld, int DIM) {
  const int row = blockIdx.x;
  const int tx = threadIdx.x;
  const float y = yp[0], b0 = bp[0];
  const float4* xr = (const float4*)(x + (size_t)row * DIM);
  const float4* er = (const float4*)e;
  float4* zr = (float4*)(z + (size_t)row * DIM);
  int cnt = 0;
  const int n4 = DIM >> 2;
  for (int k = tx; k < n4; k += blockDim.x) {
    float4 xv = xr[k], ev = er[k];
    float4 zv;
    float lin;
    lin = fmaf(y, xv.x, ev.x + b0); zv.x = lin >= 0.f ? lin : ALPHA * lin; cnt += (lin < 0.f);
    lin = fmaf(y, xv.y, ev.y + b0); zv.y = lin >= 0.f ? lin : ALPHA * lin; cnt += (lin < 0.f);
    lin = fmaf(y, xv.z, ev.z + b0); zv.z = lin >= 0.f ? lin : ALPHA * lin; cnt += (lin < 0.f);
    lin = fmaf(y, xv.w, ev.w + b0); zv.w = lin >= 0.f ? lin : ALPHA * lin; cnt += (lin < 0.f);
    zr[k] = zv;
  }
  for (int off = 32; off > 0; off >>= 1) cnt += __shfl_down(cnt, off, 64);
  __shared__ int wc[4];
  int wid = tx >> 6, lane = tx & 63;
  if (lane == 0) wc[wid] = cnt;
  __syncthreads();
  if (tx == 0) {
    int total = wc[0] + wc[1] + wc[2] + wc[3];
    ld[row] = (float)DIM * logf(fabsf(y)) + (float)total * LOG_ALPHA;
  }
}

extern "C" void kernel_launch(void* const* d_in, const int* in_sizes, int n_in,
                              void* d_out, int out_size, void* d_ws, size_t ws_size,
                              hipStream_t stream) {
  const float* x = (const float*)d_in[0];
  const float* y = (const float*)d_in[1];
  const float* w = (const float*)d_in[2];
  const float* b = (const float*)d_in[3];
  const float* u = (const float*)d_in[4];
  const float* v = (const float*)d_in[5];
  const float* a = (const float*)d_in[6];
  const int HID = in_sizes[2];            // w has HID elements
  const int DIM = in_sizes[0] / HID;      // x is [HID, DIM]

  float* ws = (float*)d_ws;
  float* F0v  = ws;            float* Dv  = ws + 1 * DIM;
  float* F0w  = ws + 2 * DIM;  float* Dw  = ws + 3 * DIM;
  float* F0v2 = ws + 4 * DIM;  float* Dv2 = ws + 5 * DIM;
  float* F0w2 = ws + 6 * DIM;  float* Dw2 = ws + 7 * DIM;
  float* d1   = ws + 8 * DIM;  float* e   = ws + 9 * DIM;

  float* z = (float*)d_out;
  float* ld = z + (size_t)HID * DIM;

  // zero the atomic-target arrays (ws is poisoned 0xAA before each call)
  int nz = 8 * DIM;
  zero_kernel<<<(nz + 255) / 256, 256, 0, stream>>>(ws, nz);

  const int RPB = 128;
  dim3 grid1(DIM / 256, HID / RPB);  // 16 x 64 = 1024 blocks
  col_stats_kernel<false><<<grid1, 256, 0, stream>>>(
      x, w, v, u, a, nullptr, F0v, Dv, F0w, Dw, DIM, RPB);
  scan_d_kernel<<<1, 64, 0, stream>>>(F0v, Dv, d1, DIM);
  col_stats_kernel<true><<<grid1, 256, 0, stream>>>(
      x, w, v, u, a, d1, F0v2, Dv2, F0w2, Dw2, DIM, RPB);
  scan_e_kernel<<<1, 64, 0, stream>>>(F0v2, Dv2, F0w2, Dw2, d1, e, DIM);
  z_kernel<<<HID, 256, 0, stream>>>(x, e, y, b, z, ld, DIM);
}

// Round 2
// 299.535 us; speedup vs baseline: 1.1781x; 1.1781x over previous
//
#include <hip/hip_runtime.h>
#include <cstdint>
#include <cstddef>

#define LOG_ALPHA -2.302585092994046f  // ln(0.1)
#define ALPHA 0.1f

__global__ void zero_kernel(float* p, int n) {
  int i = blockIdx.x * blockDim.x + threadIdx.x;
  if (i < n) p[i] = 0.f;
}

// Per column j: F0v[j] = sum_b v_b*relu(t), Dv[j] = sum_{t>0} v_b, same for w.
// t = u*x[b,j] + a. Each thread owns 4 consecutive columns (float4 loads).
__global__ __launch_bounds__(256) void col_stats_kernel(
    const float* __restrict__ x, const float* __restrict__ w,
    const float* __restrict__ v, const float* __restrict__ up,
    const float* __restrict__ ap,
    float* __restrict__ F0v, float* __restrict__ Dv,
    float* __restrict__ F0w, float* __restrict__ Dw,
    int DIM, int ROWS_PER_BLOCK) {
  const int q = blockIdx.x * blockDim.x + threadIdx.x;  // column quad
  const int r0 = blockIdx.y * ROWS_PER_BLOCK;
  const float u = up[0], a = ap[0];
  const float4* x4 = (const float4*)x;
  const int ld4 = DIM >> 2;
  float4 fv = {0, 0, 0, 0}, dv = {0, 0, 0, 0};
  float4 fw = {0, 0, 0, 0}, dw = {0, 0, 0, 0};
#pragma unroll 4
  for (int r = r0; r < r0 + ROWS_PER_BLOCK; ++r) {
    float4 xv = x4[(size_t)r * ld4 + q];  // 16 B/lane, coalesced
    float vb = v[r], wb = w[r];           // wave-uniform -> s_load
    float t, rt, m;
    t = fmaf(u, xv.x, a); rt = fmaxf(t, 0.f); m = t > 0.f ? 1.f : 0.f;
    fv.x = fmaf(vb, rt, fv.x); dv.x = fmaf(vb, m, dv.x);
    fw.x = fmaf(wb, rt, fw.x); dw.x = fmaf(wb, m, dw.x);
    t = fmaf(u, xv.y, a); rt = fmaxf(t, 0.f); m = t > 0.f ? 1.f : 0.f;
    fv.y = fmaf(vb, rt, fv.y); dv.y = fmaf(vb, m, dv.y);
    fw.y = fmaf(wb, rt, fw.y); dw.y = fmaf(wb, m, dw.y);
    t = fmaf(u, xv.z, a); rt = fmaxf(t, 0.f); m = t > 0.f ? 1.f : 0.f;
    fv.z = fmaf(vb, rt, fv.z); dv.z = fmaf(vb, m, dv.z);
    fw.z = fmaf(wb, rt, fw.z); dw.z = fmaf(wb, m, dw.z);
    t = fmaf(u, xv.w, a); rt = fmaxf(t, 0.f); m = t > 0.f ? 1.f : 0.f;
    fv.w = fmaf(vb, rt, fv.w); dv.w = fmaf(vb, m, dv.w);
    fw.w = fmaf(wb, rt, fw.w); dw.w = fmaf(wb, m, dw.w);
  }
  const int c = q << 2;
  atomicAdd(&F0v[c + 0], fv.x); atomicAdd(&F0v[c + 1], fv.y);
  atomicAdd(&F0v[c + 2], fv.z); atomicAdd(&F0v[c + 3], fv.w);
  atomicAdd(&Dv[c + 0], dv.x);  atomicAdd(&Dv[c + 1], dv.y);
  atomicAdd(&Dv[c + 2], dv.z);  atomicAdd(&Dv[c + 3], dv.w);
  atomicAdd(&F0w[c + 0], fw.x); atomicAdd(&F0w[c + 1], fw.y);
  atomicAdd(&F0w[c + 2], fw.z); atomicAdd(&F0w[c + 3], fw.w);
  atomicAdd(&Dw[c + 0], dw.x);  atomicAdd(&Dw[c + 1], dw.y);
  atomicAdd(&Dw[c + 2], dw.z);  atomicAdd(&Dw[c + 3], dw.w);
}

// Single-wave affine scan: d_{i+1} = F0v[i] + Dv[i]*d_i, d_0 = 0, then
// e_{i+1} = F0w[i] + Dw[i]*d_i during replay. e_0 = 0.
__global__ void scan_kernel(const float* __restrict__ F0v,
                            const float* __restrict__ Dv,
                            const float* __restrict__ F0w,
                            const float* __restrict__ Dw,
                            float* __restrict__ e, int DIM) {
  const int L = threadIdx.x;  // one wave: 64 lanes
  const int S = DIM >> 6;     // segment length per lane
  const int base = L * S;     // lane L consumes indices [base, base+S)
  const float4* F4 = (const float4*)F0v;
  const float4* D4 = (const float4*)Dv;
  const float4* Fw4 = (const float4*)F0w;
  const float4* Dw4 = (const float4*)Dw;
  const int q0 = base >> 2, nq = S >> 2;
  // Phase 1: compose my segment's affine map p -> B + A*p (vectorized loads)
  float A = 1.f, B = 0.f;
#pragma unroll 4
  for (int qq = 0; qq < nq; ++qq) {
    float4 f = F4[q0 + qq], dd = D4[q0 + qq];
    B = fmaf(dd.x, B, f.x); A *= dd.x;
    B = fmaf(dd.y, B, f.y); A *= dd.y;
    B = fmaf(dd.z, B, f.z); A *= dd.z;
    B = fmaf(dd.w, B, f.w); A *= dd.w;
  }
  // Inclusive composition scan across lanes
  for (int off = 1; off < 64; off <<= 1) {
    float Ao = __shfl_up(A, off, 64);
    float Bo = __shfl_up(B, off, 64);
    if (L >= off) { B = fmaf(A, Bo, B); A = A * Ao; }
  }
  float d = __shfl_up(B, 1, 64);  // d at my segment start (d_0 applied up to lane L-1)
  if (L == 0) d = 0.f;
  // Phase 2: replay, emitting e_{j+1} = F0w[j] + Dw[j]*d_j
  if (L == 0) e[0] = 0.f;
#pragma unroll 4
  for (int qq = 0; qq < nq; ++qq) {
    float4 f = F4[q0 + qq], dd = D4[q0 + qq];
    float4 fw = Fw4[q0 + qq], dwv = Dw4[q0 + qq];
    int j = base + (qq << 2);
    if (j + 1 < DIM) e[j + 1] = fmaf(dwv.x, d, fw.x);
    d = fmaf(dd.x, d, f.x);
    if (j + 2 < DIM) e[j + 2] = fmaf(dwv.y, d, fw.y);
    d = fmaf(dd.y, d, f.y);
    if (j + 3 < DIM) e[j + 3] = fmaf(dwv.z, d, fw.z);
    d = fmaf(dd.z, d, f.z);
    if (j + 4 < DIM) e[j + 4] = fmaf(dwv.w, d, fw.w);
    d = fmaf(dd.w, d, f.w);
  }
}

// Wait: phase-2 above advances d BEFORE using it for the next e. Check:
// entering iteration element j: d == d_j. e_{j+1} = F0w[j]+Dw[j]*d_j  (uses d_j,
// BEFORE advancing), then d_{j+1} = F0v[j]+Dv[j]*d_j. Order in code: e then d. OK.

// z[b,i] = leakyrelu(y*x[b,i] + e_i + b0); ld[b] = DIM*log|y| + cnt_neg*ln(alpha)
__global__ __launch_bounds__(256) void z_kernel(
    const float* __restrict__ x, const float* __restrict__ e,
    const float* __restrict__ yp, const float* __restrict__ bp,
    float* __restrict__ z, float* __restrict__ ld, int DIM) {
  const int row = blockIdx.x;
  const int tx = threadIdx.x;
  const float y = yp[0], b0 = bp[0];
  const float4* xr = (const float4*)(x + (size_t)row * DIM);
  const float4* er = (const float4*)e;
  float4* zr = (float4*)(z + (size_t)row * DIM);
  int cnt = 0;
  const int n4 = DIM >> 2;
  for (int k = tx; k < n4; k += blockDim.x) {
    float4 xv = xr[k], ev = er[k];
    float4 zv;
    float lin;
    lin = fmaf(y, xv.x, ev.x + b0); zv.x = lin >= 0.f ? lin : ALPHA * lin; cnt += (lin < 0.f);
    lin = fmaf(y, xv.y, ev.y + b0); zv.y = lin >= 0.f ? lin : ALPHA * lin; cnt += (lin < 0.f);
    lin = fmaf(y, xv.z, ev.z + b0); zv.z = lin >= 0.f ? lin : ALPHA * lin; cnt += (lin < 0.f);
    lin = fmaf(y, xv.w, ev.w + b0); zv.w = lin >= 0.f ? lin : ALPHA * lin; cnt += (lin < 0.f);
    zr[k] = zv;
  }
  for (int off = 32; off > 0; off >>= 1) cnt += __shfl_down(cnt, off, 64);
  __shared__ int wc[4];
  int wid = tx >> 6, lane = tx & 63;
  if (lane == 0) wc[wid] = cnt;
  __syncthreads();
  if (tx == 0) {
    int total = wc[0] + wc[1] + wc[2] + wc[3];
    ld[row] = (float)DIM * logf(fabsf(y)) + (float)total * LOG_ALPHA;
  }
}

extern "C" void kernel_launch(void* const* d_in, const int* in_sizes, int n_in,
                              void* d_out, int out_size, void* d_ws, size_t ws_size,
                              hipStream_t stream) {
  const float* x = (const float*)d_in[0];
  const float* y = (const float*)d_in[1];
  const float* w = (const float*)d_in[2];
  const float* b = (const float*)d_in[3];
  const float* u = (const float*)d_in[4];
  const float* v = (const float*)d_in[5];
  const float* a = (const float*)d_in[6];
  const int HID = in_sizes[2];         // w has HID elements
  const int DIM = in_sizes[0] / HID;   // x is [HID, DIM]

  float* ws = (float*)d_ws;
  float* F0v = ws;           float* Dv = ws + 1 * DIM;
  float* F0w = ws + 2 * DIM; float* Dw = ws + 3 * DIM;
  float* e   = ws + 4 * DIM;

  float* z = (float*)d_out;
  float* ld = z + (size_t)HID * DIM;

  // zero the atomic-target arrays (ws is poisoned 0xAA before each call)
  int nz = 4 * DIM;
  zero_kernel<<<(nz + 255) / 256, 256, 0, stream>>>(ws, nz);

  // 4 col-quads-per-thread layout: grid.x = DIM/(256*4); RPB=64 -> 512 blocks
  const int RPB = 64;
  dim3 grid1(DIM / (256 * 4), HID / RPB);
  col_stats_kernel<<<grid1, 256, 0, stream>>>(
      x, w, v, u, a, F0v, Dv, F0w, Dw, DIM, RPB);
  scan_kernel<<<1, 64, 0, stream>>>(F0v, Dv, F0w, Dw, e, DIM);
  z_kernel<<<HID, 256, 0, stream>>>(x, e, y, b, z, ld, DIM);
}